// Round 17
// baseline (336.393 us; speedup 1.0000x reference)
//
#include <hip/hip_runtime.h>
#include <math.h>

#define NP 256   // datapoints
#define BB 128   // batch
#define DD 784   // dims
#define HS_MIN 1e-7f
#define LOG_HS_MIN -16.11809565095832f   // log(1e-7)
#define LOG_MB -16.811242831518264f      // log(5e-8) — mask bound in log space
#define NEG_HALF_LOG_2PI -0.9189385332046727f
#define W 8      // householder window
#define NW 98    // 784/8
#define TILE_F (W * DD)   // 6272 floats per window tile
#define TBUF_F 6400       // LDS buffer stride: 25 chunks x 256 floats

// ---------------- ndtri (AS241, double poly) from log_cdf / log_sf ----------------
__device__ double ndtri_logs(float log_cdf_f, float log_sf_f) {
    double lp = (double)log_cdf_f;
    double ls = (double)log_sf_f;
    double p = (double)__expf(log_cdf_f);
    double q = p - 0.5;
    if (fabs(q) <= 0.425) {
        double r = 0.180625 - q * q;
        double num = (((((((2.5090809287301226727e3 * r + 3.3430575583588128105e4) * r
                         + 6.7265770927008700853e4) * r + 4.5921953931549871457e4) * r
                         + 1.3731693765509461125e4) * r + 1.9715909503065514427e3) * r
                         + 1.3314166789178437745e2) * r + 3.3871328727963666080e0);
        double den = (((((((5.2264952788528545610e3 * r + 2.8729085735721942674e4) * r
                         + 3.9307895800092710610e4) * r + 2.1213794301586595867e4) * r
                         + 5.3941960214247511077e3) * r + 6.8718700749205790830e2) * r
                         + 4.2313330701600911252e1) * r + 1.0);
        return q * num / den;
    }
    // tail: r = sqrt(-log(min(p,1-p))) straight from the log — no 1-p cancellation
    double r = (q < 0.0) ? sqrt(-lp) : sqrt(-ls);
    double v;
    if (r <= 5.0) {
        r -= 1.6;
        double num = (((((((7.74545014278341407640e-4 * r + 2.27238449892691845833e-2) * r
                         + 2.41780725177450611770e-1) * r + 1.27045825245236838258e0) * r
                         + 3.64784832476320460504e0) * r + 5.76949722146069140550e0) * r
                         + 4.63033784615654529590e0) * r + 1.42343711074968357734e0);
        double den = (((((((1.05075007164441684324e-9 * r + 5.47593808499534494600e-4) * r
                         + 1.51986665636164571966e-2) * r + 1.48103976427480074590e-1) * r
                         + 6.89767334985100004550e-1) * r + 1.67638483018380384940e0) * r
                         + 2.05319162663775882187e0) * r + 1.0);
        v = num / den;
    } else {
        r -= 5.0;
        double num = (((((((2.01033439929228813265e-7 * r + 2.71155556874348757815e-5) * r
                         + 1.24266094738807843860e-3) * r + 2.65321895265761230930e-2) * r
                         + 2.96560571828504891230e-1) * r + 1.78482653991729133580e0) * r
                         + 5.46378491116411436990e0) * r + 6.65790464350110377720e0);
        double den = (((((((2.04426310338993978564e-15 * r + 1.42151175831644588870e-7) * r
                         + 1.84631831751005468180e-5) * r + 7.86869131145613259100e-4) * r
                         + 1.48753612908506148525e-2) * r + 1.36929880922735805310e-1) * r
                         + 5.99832206555887937690e-1) * r + 1.0);
        v = num / den;
    }
    return (q < 0.0) ? -v : v;
}

// ---------------- K0: lsew[d] = logsumexp_n kde_weights[n,d] (block per d) ----------------
__global__ __launch_bounds__(256) void k_lsew(const float* __restrict__ kw,
                                              float* __restrict__ lsew) {
    __shared__ float red[4];
    int d = blockIdx.x;
    int n = threadIdx.x;          // NP == 256 == blockDim
    float a = kw[n * DD + d];
    float m = a;
    #pragma unroll
    for (int off = 32; off; off >>= 1) m = fmaxf(m, __shfl_xor(m, off, 64));
    if ((threadIdx.x & 63) == 0) red[threadIdx.x >> 6] = m;
    __syncthreads();
    m = fmaxf(fmaxf(red[0], red[1]), fmaxf(red[2], red[3]));
    __syncthreads();
    float e = __expf(a - m);
    #pragma unroll
    for (int off = 32; off; off >>= 1) e += __shfl_xor(e, off, 64);
    if ((threadIdx.x & 63) == 0) red[threadIdx.x >> 6] = e;
    __syncthreads();
    if (threadIdx.x == 0)
        lsew[d] = m + __logf(red[0] + red[1] + red[2] + red[3]);
}

// ---------------- K1: per-(n,d) precompute, packed float4 {dp, 1/hs, w, w-lhc} ----------------
__global__ __launch_bounds__(256) void k_prep(const float* __restrict__ kw,
                                              const float* __restrict__ log_hs,
                                              const float* __restrict__ dp,
                                              const float* __restrict__ lsew,
                                              float4* __restrict__ pk) {
    int n = blockIdx.x;
    for (int d = threadIdx.x; d < DD; d += 256) {
        int idx = n * DD + d;
        float lh = log_hs[idx];
        float hs = fmaxf(__expf(lh), HS_MIN);
        float lhc = fmaxf(lh, LOG_HS_MIN);
        float wv = kw[idx] - lsew[d];
        pk[idx] = make_float4(dp[idx], 1.f / hs, wv, wv - lhc);
    }
}

// ---------------- K2: main KDE + inverse + term ----------------
__global__ __launch_bounds__(256) void k_main(const float* __restrict__ x,
                                              const float4* __restrict__ pk,
                                              float* __restrict__ Y,
                                              float* __restrict__ T) {
    unsigned t = blockIdx.x * 256u + threadIdx.x;   // t < B*D exactly
    unsigned b = t / DD;
    unsigned d = t - b * DD;
    float xv = x[t];
    float m1 = -INFINITY, s1 = 0.f;
    float m2 = -INFINITY, s2 = 0.f;
    float m3 = -INFINITY, s3 = 0.f;
    for (int n = 0; n < NP; ++n) {
        float4 c = pk[n * DD + d];          // {dp, ihs, w, w-lhc}
        float u = (c.x - xv) * c.y;
        float e = __expf(-fabsf(u));
        float l1p = __logf(1.f + e);
        float sp = fmaxf(u, 0.f) + l1p;
        float a1 = c.z - sp;
        float a2 = fminf(u, 0.f) - l1p + c.z;
        float a3 = u - 2.f * sp + c.w;
        float nm;
        nm = fmaxf(m1, a1); s1 = s1 * __expf(m1 - nm) + __expf(a1 - nm); m1 = nm;
        nm = fmaxf(m2, a2); s2 = s2 * __expf(m2 - nm) + __expf(a2 - nm); m2 = nm;
        nm = fmaxf(m3, a3); s3 = s3 * __expf(m3 - nm) + __expf(a3 - nm); m3 = nm;
    }
    float log_cdf = m1 + __logf(s1);
    float log_sf  = m2 + __logf(s2);
    float log_pdf = m3 + __logf(s3);

    // log-space mask classification (no f32 cancellation at cdf ~ 1)
    bool right = (log_sf  <= LOG_MB);
    bool left  = (log_cdf <= LOG_MB);

    float inv, lgd;
    if (right) {
        float t2 = -2.f * log_sf;
        inv = sqrtf(t2);
        lgd = 0.5f * __logf(t2) - log_sf;
    } else if (left) {
        float t2 = -2.f * log_cdf;
        inv = -sqrtf(t2);
        lgd = 0.5f * __logf(t2) - log_cdf;
    } else {
        inv = (float)ndtri_logs(log_cdf, log_sf);
        lgd = -0.5f * inv * inv + NEG_HALF_LOG_2PI;
    }
    Y[t] = inv;
    T[t] = log_pdf - lgd;
}

// ---------------- K3: log_det reduction ----------------
__global__ __launch_bounds__(256) void k_logdet(const float* __restrict__ T,
                                                const float* __restrict__ ld_in,
                                                float* __restrict__ out) {
    __shared__ float red[4];
    int b = blockIdx.x;
    float s = 0.f;
    for (int d = threadIdx.x; d < DD; d += 256) s += T[b * DD + d];
    #pragma unroll
    for (int off = 32; off; off >>= 1) s += __shfl_down(s, off, 64);
    if ((threadIdx.x & 63) == 0) red[threadIdx.x >> 6] = s;
    __syncthreads();
    if (threadIdx.x == 0) out[BB * DD + b] = ld_in[b] + red[0] + red[1] + red[2] + red[3];
}

// ---------------- K4: normalize reflector rows ----------------
__global__ __launch_bounds__(256) void k_vn(const float* __restrict__ vs,
                                            float* __restrict__ vn) {
    __shared__ float red[4];
    int i = blockIdx.x;
    float ss = 0.f;
    for (int j = threadIdx.x; j < DD; j += 256) {
        float v = vs[i * DD + j];
        ss += v * v;
    }
    #pragma unroll
    for (int off = 32; off; off >>= 1) ss += __shfl_down(ss, off, 64);
    if ((threadIdx.x & 63) == 0) red[threadIdx.x >> 6] = ss;
    __syncthreads();
    float inorm = rsqrtf(red[0] + red[1] + red[2] + red[3]);
    for (int j = threadIdx.x; j < DD; j += 256)
        vn[i * DD + j] = vs[i * DD + j] * inorm;
}

// ---------------- K5: Gram of each 8-reflector window (same math, W=8 blocks) ----------------
__global__ __launch_bounds__(64) void k_gram(const float* __restrict__ vn,
                                             float* __restrict__ G) {
    int wi = blockIdx.x;          // 0..97
    int t = threadIdx.x;          // 64 = 8x8
    int k = t >> 3, i = t & 7;
    const float4* a = (const float4*)(vn + (wi * W + k) * DD);
    const float4* b = (const float4*)(vn + (wi * W + i) * DD);
    float s = 0.f;
    for (int j = 0; j < DD / 4; ++j) {
        float4 av = a[j], bv = b[j];
        s += av.x * bv.x + av.y * bv.y + av.z * bv.z + av.w * bv.w;
    }
    G[wi * 64 + k * 8 + i] = s;   // G[w][k][i] = v_k . v_i
}

// ---------------- DPP wave64 sum: 6 VALU steps + readlane (no LDS pipe) ----------------
// Verified rounds 10/11/13/14/15/16 (passed, absmax 1.0). Full 64-lane sum, wave-uniform.
__device__ __forceinline__ float wave_red_sum(float x) {
    x += __int_as_float(__builtin_amdgcn_update_dpp(0, __float_as_int(x), 0x111, 0xf, 0xf, true));
    x += __int_as_float(__builtin_amdgcn_update_dpp(0, __float_as_int(x), 0x112, 0xf, 0xf, true));
    x += __int_as_float(__builtin_amdgcn_update_dpp(0, __float_as_int(x), 0x114, 0xf, 0xf, true));
    x += __int_as_float(__builtin_amdgcn_update_dpp(0, __float_as_int(x), 0x118, 0xf, 0xf, true));
    x += __int_as_float(__builtin_amdgcn_update_dpp(0, __float_as_int(x), 0x142, 0xa, 0xf, true));
    x += __int_as_float(__builtin_amdgcn_update_dpp(0, __float_as_int(x), 0x143, 0xc, 0xf, true));
    return __int_as_float(__builtin_amdgcn_readlane(__float_as_int(x), 63));
}

// ---------------- K6: Householder chain — LDS-V via global_load_lds + G in LDS ----------------
// Round-15 residual model (confirmed by the 177→131 G-LDS win): 3.2k cy/window =
// compute ~1.1k + TWO phases x ~4 register-starved L2 load batches x ~250 cy. Six
// attempts prove the allocator won't give V more than ~11 float4 slots. Fix: take the
// register file out of the V path entirely — global_load_lds stages the window tile
// into a double-buffered LDS region with ZERO VGPR involvement. Round 4 tried this
// and failed (291us) because its substitution read G from GLOBAL inside each window:
// that vmcnt wait (in-order counter) drained the just-issued glds prefetch every
// window, making staging synchronous. With G in LDS (round 15's fix) there is NO
// global wait inside the window: the top-of-window vmcnt(0) targets staging issued a
// full window (~2k cy) earlier -> retired. Compute reads V from LDS in both phases
// (ds_read_b128 x3 + tail; re-read is cheap). Math value-identical to round 15:
// same V bits (LDS passes them through), same accumulation order, same DPP tree,
// same substitution association. Single wave, zero barriers.
__device__ __forceinline__ void stage_v(const float* __restrict__ VN, int wi,
                                        float* buf, int l) {
    const float* src = VN + (size_t)wi * TILE_F;
    // 25 chunks x (64 lanes x 16B) = 25600 floats... 6400 floats = 25.6KB; chunk 24
    // overreads 128 floats past the 6272-float tile: lands in the next window's V
    // (for wi=97: in the G workspace region, allocated). Pad floats are never read.
    #pragma unroll
    for (int c = 0; c < 25; ++c) {
        __builtin_amdgcn_global_load_lds(
            (const __attribute__((address_space(1))) void*)(src + c * 256 + l * 4),
            (__attribute__((address_space(3))) void*)(buf + c * 256),
            16, 0, 0);
    }
}

__global__ __launch_bounds__(64, 1) void k_house(const float* __restrict__ Yin,
                                                 const float* __restrict__ VN,
                                                 const float* __restrict__ G,
                                                 float* __restrict__ out) {
    __shared__ float vb[2][TBUF_F];       // 51200 B: double-buffered V tile
    __shared__ float gld[NW * 64];        // 25088 B: entire G table, staged once
    const int b = blockIdx.x;
    const int l = threadIdx.x;
    const int toff = 768 + (l & 15);      // clamped tail address (in-bounds all lanes)
    const bool thas = (l < 16);

    // one-time G stage: 98 coalesced dword loads per lane-stripe
    for (int i = l; i < NW * 64; i += 64) gld[i] = G[i];

    float4 y[3];
    float ytl;
    #pragma unroll
    for (int i = 0; i < 3; ++i)
        y[i] = *(const float4*)(Yin + b * DD + 256 * i + 4 * l);
    ytl = thas ? Yin[b * DD + toff] : 0.f;

    stage_v(VN, 0, vb[0], l);

    for (int wi = 0; wi < NW; ++wi) {
        // wait for current buffer's staging (issued one full window ago — near-zero stall)
        asm volatile("s_waitcnt vmcnt(0)" ::: "memory");
        __builtin_amdgcn_sched_barrier(0);
        if (wi + 1 < NW) stage_v(VN, wi + 1, vb[(wi + 1) & 1], l);

        const float* bw = vb[wi & 1];
        const float* Gw = gld + wi * 64;

        // raw dots q_r = y . v_r from LDS; same accumulation order as round 15
        float p[W];
        #pragma unroll
        for (int r = 0; r < W; ++r) {
            const float* vr = bw + r * DD;
            float4 a0 = *(const float4*)(vr + 4 * l);
            float4 a1 = *(const float4*)(vr + 256 + 4 * l);
            float4 a2 = *(const float4*)(vr + 512 + 4 * l);
            float vt = thas ? vr[toff] : 0.f;
            float s = 0.f;
            s += y[0].x * a0.x + y[0].y * a0.y + y[0].z * a0.z + y[0].w * a0.w;
            s += y[1].x * a1.x + y[1].y * a1.y + y[1].z * a1.z + y[1].w * a1.w;
            s += y[2].x * a2.x + y[2].y * a2.y + y[2].z * a2.z + y[2].w * a2.w;
            s += ytl * vt;                    // 0 on lanes >= 16
            p[r] = wave_red_sum(s);
        }

        // forward substitution (same formula & association as verified rounds), G from LDS
        float sv[W];
        #pragma unroll
        for (int r = 0; r < W; ++r) {
            float acc = p[r];
            #pragma unroll
            for (int k = 0; k < W; ++k)
                if (k < r) acc -= 2.f * Gw[k * 8 + r] * sv[k];
            sv[r] = acc;
        }

        // rank-8 update: re-read V from LDS (cheap, same bits as dot phase)
        #pragma unroll
        for (int r = 0; r < W; ++r) {
            const float* vr = bw + r * DD;
            float c = 2.f * sv[r];
            float4 a0 = *(const float4*)(vr + 4 * l);
            float4 a1 = *(const float4*)(vr + 256 + 4 * l);
            float4 a2 = *(const float4*)(vr + 512 + 4 * l);
            y[0].x -= c * a0.x;  y[0].y -= c * a0.y;  y[0].z -= c * a0.z;  y[0].w -= c * a0.w;
            y[1].x -= c * a1.x;  y[1].y -= c * a1.y;  y[1].z -= c * a1.z;  y[1].w -= c * a1.w;
            y[2].x -= c * a2.x;  y[2].y -= c * a2.y;  y[2].z -= c * a2.z;  y[2].w -= c * a2.w;
            if (thas) ytl -= c * vr[toff];
        }
    }

    #pragma unroll
    for (int i = 0; i < 3; ++i)
        *(float4*)(out + b * DD + 256 * i + 4 * l) = y[i];
    if (thas)
        out[b * DD + toff] = ytl;
}

// ---------------- launch ----------------
extern "C" void kernel_launch(void* const* d_in, const int* in_sizes, int n_in,
                              void* d_out, int out_size, void* d_ws, size_t ws_size,
                              hipStream_t stream) {
    const float* x      = (const float*)d_in[0];   // [B,D]
    const float* ld_in  = (const float*)d_in[1];   // [B]
    const float* dp     = (const float*)d_in[2];   // [N,D]
    const float* log_hs = (const float*)d_in[3];   // [N,D]
    const float* kw     = (const float*)d_in[4];   // [N,D]
    const float* vs     = (const float*)d_in[5];   // [D,D]
    float* out = (float*)d_out;                    // x_out [B,D] then log_det [B]

    float* ws   = (float*)d_ws;
    float* lsew = ws;                         // 784 (pad to 1024)
    float4* pk  = (float4*)(ws + 1024);       // N*D float4
    float* Y    = ws + 1024 + NP * DD * 4;    // B*D
    float* T    = Y + BB * DD;                // B*D
    float* VN   = T + BB * DD;                // D*D
    float* G    = VN + DD * DD;               // NW*64 = 6272 (also absorbs stage over-read pad)

    k_lsew<<<DD, 256, 0, stream>>>(kw, lsew);
    k_prep<<<NP, 256, 0, stream>>>(kw, log_hs, dp, lsew, pk);
    k_main<<<(BB * DD) / 256, 256, 0, stream>>>(x, pk, Y, T);
    k_logdet<<<BB, 256, 0, stream>>>(T, ld_in, out);
    k_vn<<<DD, 256, 0, stream>>>(vs, VN);
    k_gram<<<NW, 64, 0, stream>>>(VN, G);
    k_house<<<BB, 64, 0, stream>>>(Y, VN, G, out);
}

// Round 18
// 258.148 us; speedup vs baseline: 1.3031x; 1.3031x over previous
//
#include <hip/hip_runtime.h>
#include <math.h>

#define NP 256   // datapoints
#define BB 128   // batch
#define DD 784   // dims
#define HS_MIN 1e-7f
#define LOG_HS_MIN -16.11809565095832f   // log(1e-7)
#define LOG_MB -16.811242831518264f      // log(5e-8) — mask bound in log space
#define NEG_HALF_LOG_2PI -0.9189385332046727f
#define W 8      // householder window
#define NW 98    // 784/8

// ---------------- ndtri (AS241, double poly) from log_cdf / log_sf ----------------
__device__ double ndtri_logs(float log_cdf_f, float log_sf_f) {
    double lp = (double)log_cdf_f;
    double ls = (double)log_sf_f;
    double p = (double)__expf(log_cdf_f);
    double q = p - 0.5;
    if (fabs(q) <= 0.425) {
        double r = 0.180625 - q * q;
        double num = (((((((2.5090809287301226727e3 * r + 3.3430575583588128105e4) * r
                         + 6.7265770927008700853e4) * r + 4.5921953931549871457e4) * r
                         + 1.3731693765509461125e4) * r + 1.9715909503065514427e3) * r
                         + 1.3314166789178437745e2) * r + 3.3871328727963666080e0);
        double den = (((((((5.2264952788528545610e3 * r + 2.8729085735721942674e4) * r
                         + 3.9307895800092710610e4) * r + 2.1213794301586595867e4) * r
                         + 5.3941960214247511077e3) * r + 6.8718700749205790830e2) * r
                         + 4.2313330701600911252e1) * r + 1.0);
        return q * num / den;
    }
    // tail: r = sqrt(-log(min(p,1-p))) straight from the log — no 1-p cancellation
    double r = (q < 0.0) ? sqrt(-lp) : sqrt(-ls);
    double v;
    if (r <= 5.0) {
        r -= 1.6;
        double num = (((((((7.74545014278341407640e-4 * r + 2.27238449892691845833e-2) * r
                         + 2.41780725177450611770e-1) * r + 1.27045825245236838258e0) * r
                         + 3.64784832476320460504e0) * r + 5.76949722146069140550e0) * r
                         + 4.63033784615654529590e0) * r + 1.42343711074968357734e0);
        double den = (((((((1.05075007164441684324e-9 * r + 5.47593808499534494600e-4) * r
                         + 1.51986665636164571966e-2) * r + 1.48103976427480074590e-1) * r
                         + 6.89767334985100004550e-1) * r + 1.67638483018380384940e0) * r
                         + 2.05319162663775882187e0) * r + 1.0);
        v = num / den;
    } else {
        r -= 5.0;
        double num = (((((((2.01033439929228813265e-7 * r + 2.71155556874348757815e-5) * r
                         + 1.24266094738807843860e-3) * r + 2.65321895265761230930e-2) * r
                         + 2.96560571828504891230e-1) * r + 1.78482653991729133580e0) * r
                         + 5.46378491116411436990e0) * r + 6.65790464350110377720e0);
        double den = (((((((2.04426310338993978564e-15 * r + 1.42151175831644588870e-7) * r
                         + 1.84631831751005468180e-5) * r + 7.86869131145613259100e-4) * r
                         + 1.48753612908506148525e-2) * r + 1.36929880922735805310e-1) * r
                         + 5.99832206555887937690e-1) * r + 1.0);
        v = num / den;
    }
    return (q < 0.0) ? -v : v;
}

// ---------------- K0: lsew[d] = logsumexp_n kde_weights[n,d] (block per d) ----------------
__global__ __launch_bounds__(256) void k_lsew(const float* __restrict__ kw,
                                              float* __restrict__ lsew) {
    __shared__ float red[4];
    int d = blockIdx.x;
    int n = threadIdx.x;          // NP == 256 == blockDim
    float a = kw[n * DD + d];
    float m = a;
    #pragma unroll
    for (int off = 32; off; off >>= 1) m = fmaxf(m, __shfl_xor(m, off, 64));
    if ((threadIdx.x & 63) == 0) red[threadIdx.x >> 6] = m;
    __syncthreads();
    m = fmaxf(fmaxf(red[0], red[1]), fmaxf(red[2], red[3]));
    __syncthreads();
    float e = __expf(a - m);
    #pragma unroll
    for (int off = 32; off; off >>= 1) e += __shfl_xor(e, off, 64);
    if ((threadIdx.x & 63) == 0) red[threadIdx.x >> 6] = e;
    __syncthreads();
    if (threadIdx.x == 0)
        lsew[d] = m + __logf(red[0] + red[1] + red[2] + red[3]);
}

// ---------------- K1: per-(n,d) precompute, packed float4 {dp, 1/hs, exp(w), exp(w-lhc)} ----------------
// Closed-form logistic-KDE factors: all three lse accumulands have sigmoid forms
// (see k_main), so the per-(n,d) weight factors exp(w) and exp(w-lhc) are hoisted here.
// Guarantee: max_n w = kw_max - lse >= -log(256) = -5.55, so exp(w) never all-underflows.
__global__ __launch_bounds__(256) void k_prep(const float* __restrict__ kw,
                                              const float* __restrict__ log_hs,
                                              const float* __restrict__ dp,
                                              const float* __restrict__ lsew,
                                              float4* __restrict__ pk) {
    int n = blockIdx.x;
    for (int d = threadIdx.x; d < DD; d += 256) {
        int idx = n * DD + d;
        float lh = log_hs[idx];
        float hs = fmaxf(__expf(lh), HS_MIN);
        float lhc = fmaxf(lh, LOG_HS_MIN);
        float wv = kw[idx] - lsew[d];
        pk[idx] = make_float4(dp[idx], 1.f / hs, __expf(wv), __expf(wv - lhc));
    }
}

// ---------------- K2: main KDE + inverse + term — sigmoid closed form ----------------
// With e = exp(-|u|), r = 1/(1+e):
//   exp(w - sp)                = ew  * r * (u>=0 ? e : 1)   // cdf term = ew*sigmoid(-u)
//   exp(min(u,0) - l1p + w)    = ew  * r * (u>=0 ? 1 : e)   // sf  term = ew*sigmoid(u)
//   exp(u - 2sp + w - lhc)     = ewl * e * r^2              // pdf term (symmetric in u)
// One exp + one rcp per inner iteration (was 8 transcendentals with online-max).
// Fixed-shift accumulation is safe: max_n w >= -5.55 bounds s1,s2 away from total
// underflow; ewl <= exp(16.12) and e*r^2 <= 0.25 bound s3 <= ~6e8 (no overflow).
__global__ __launch_bounds__(256) void k_main(const float* __restrict__ x,
                                              const float4* __restrict__ pk,
                                              float* __restrict__ Y,
                                              float* __restrict__ T) {
    unsigned t = blockIdx.x * 256u + threadIdx.x;   // t < B*D exactly
    unsigned b = t / DD;
    unsigned d = t - b * DD;
    float xv = x[t];
    float s1 = 0.f, s2 = 0.f, s3 = 0.f;
    for (int n = 0; n < NP; ++n) {
        float4 c = pk[n * DD + d];          // {dp, ihs, ew, ewl}
        float u = (c.x - xv) * c.y;
        float e = __expf(-fabsf(u));
        float r = 1.f / (1.f + e);
        float base = c.z * r;
        float eh = (u >= 0.f) ? e : 1.f;
        float el = (u >= 0.f) ? 1.f : e;
        s1 += base * eh;
        s2 += base * el;
        s3 += c.w * (e * r * r);
    }
    float log_cdf = __logf(s1);
    float log_sf  = __logf(s2);
    float log_pdf = __logf(s3);

    // log-space mask classification (no f32 cancellation at cdf ~ 1)
    bool right = (log_sf  <= LOG_MB);
    bool left  = (log_cdf <= LOG_MB);

    float inv, lgd;
    if (right) {
        float t2 = -2.f * log_sf;
        inv = sqrtf(t2);
        lgd = 0.5f * __logf(t2) - log_sf;
    } else if (left) {
        float t2 = -2.f * log_cdf;
        inv = -sqrtf(t2);
        lgd = 0.5f * __logf(t2) - log_cdf;
    } else {
        inv = (float)ndtri_logs(log_cdf, log_sf);
        lgd = -0.5f * inv * inv + NEG_HALF_LOG_2PI;
    }
    Y[t] = inv;
    T[t] = log_pdf - lgd;
}

// ---------------- K3: log_det reduction ----------------
__global__ __launch_bounds__(256) void k_logdet(const float* __restrict__ T,
                                                const float* __restrict__ ld_in,
                                                float* __restrict__ out) {
    __shared__ float red[4];
    int b = blockIdx.x;
    float s = 0.f;
    for (int d = threadIdx.x; d < DD; d += 256) s += T[b * DD + d];
    #pragma unroll
    for (int off = 32; off; off >>= 1) s += __shfl_down(s, off, 64);
    if ((threadIdx.x & 63) == 0) red[threadIdx.x >> 6] = s;
    __syncthreads();
    if (threadIdx.x == 0) out[BB * DD + b] = ld_in[b] + red[0] + red[1] + red[2] + red[3];
}

// ---------------- K4: normalize reflector rows ----------------
__global__ __launch_bounds__(256) void k_vn(const float* __restrict__ vs,
                                            float* __restrict__ vn) {
    __shared__ float red[4];
    int i = blockIdx.x;
    float ss = 0.f;
    for (int j = threadIdx.x; j < DD; j += 256) {
        float v = vs[i * DD + j];
        ss += v * v;
    }
    #pragma unroll
    for (int off = 32; off; off >>= 1) ss += __shfl_down(ss, off, 64);
    if ((threadIdx.x & 63) == 0) red[threadIdx.x >> 6] = ss;
    __syncthreads();
    float inorm = rsqrtf(red[0] + red[1] + red[2] + red[3]);
    for (int j = threadIdx.x; j < DD; j += 256)
        vn[i * DD + j] = vs[i * DD + j] * inorm;
}

// ---------------- K5: Gram of each 8-reflector window (same math, W=8 blocks) ----------------
__global__ __launch_bounds__(64) void k_gram(const float* __restrict__ vn,
                                             float* __restrict__ G) {
    int wi = blockIdx.x;          // 0..97
    int t = threadIdx.x;          // 64 = 8x8
    int k = t >> 3, i = t & 7;
    const float4* a = (const float4*)(vn + (wi * W + k) * DD);
    const float4* b = (const float4*)(vn + (wi * W + i) * DD);
    float s = 0.f;
    for (int j = 0; j < DD / 4; ++j) {
        float4 av = a[j], bv = b[j];
        s += av.x * bv.x + av.y * bv.y + av.z * bv.z + av.w * bv.w;
    }
    G[wi * 64 + k * 8 + i] = s;   // G[w][k][i] = v_k . v_i
}

// ---------------- DPP wave64 sum: 6 VALU steps + readlane (no LDS pipe) ----------------
// Verified rounds 10/11/13/14/15/16 (passed, absmax 1.0). Full 64-lane sum, wave-uniform.
__device__ __forceinline__ float wave_red_sum(float x) {
    x += __int_as_float(__builtin_amdgcn_update_dpp(0, __float_as_int(x), 0x111, 0xf, 0xf, true));
    x += __int_as_float(__builtin_amdgcn_update_dpp(0, __float_as_int(x), 0x112, 0xf, 0xf, true));
    x += __int_as_float(__builtin_amdgcn_update_dpp(0, __float_as_int(x), 0x114, 0xf, 0xf, true));
    x += __int_as_float(__builtin_amdgcn_update_dpp(0, __float_as_int(x), 0x118, 0xf, 0xf, true));
    x += __int_as_float(__builtin_amdgcn_update_dpp(0, __float_as_int(x), 0x142, 0xa, 0xf, true));
    x += __int_as_float(__builtin_amdgcn_update_dpp(0, __float_as_int(x), 0x143, 0xc, 0xf, true));
    return __int_as_float(__builtin_amdgcn_readlane(__float_as_int(x), 63));
}

// ---------------- K6: Householder chain — round-15 EXACT (best verified: 131us) ----------------
// Seven k_house structures (rounds 6/7/9/11/13/14/17) bracket this one: 131us is the
// floor for the latency-serial 98-window chain on this allocator. G staged to LDS once
// (the round-15 win: removes the per-window vmcnt drain of the V pipeline); V loads
// implicit with remat. Do not touch.
__global__ __launch_bounds__(64, 1) void k_house(const float* __restrict__ Yin,
                                                 const float* __restrict__ VN,
                                                 const float* __restrict__ G,
                                                 float* __restrict__ out) {
    __shared__ float gld[NW * 64];        // 25088 B: entire G table, staged once
    const int b = blockIdx.x;
    const int l = threadIdx.x;
    const int toff = 768 + (l & 15);      // clamped tail address (in-bounds all lanes)
    const bool thas = (l < 16);

    // one-time G stage: 98 coalesced dword loads per lane-stripe
    for (int i = l; i < NW * 64; i += 64) gld[i] = G[i];
    __syncthreads();

    float4 y[3];
    float ytl;
    #pragma unroll
    for (int i = 0; i < 3; ++i)
        y[i] = *(const float4*)(Yin + b * DD + 256 * i + 4 * l);
    ytl = thas ? Yin[b * DD + toff] : 0.f;

    for (int wi = 0; wi < NW; ++wi) {
        const float* Vw = VN + (size_t)wi * (W * DD);
        const float* Gw = gld + wi * 64;  // LDS: substitution never touches vmcnt

        // window's 8 V rows: 3 float4 + 1 tail scalar per lane (104 floats)
        float4 v[W][3];
        float vt[W];
        #pragma unroll
        for (int r = 0; r < W; ++r) {
            const float* vr = Vw + r * DD;
            #pragma unroll
            for (int i = 0; i < 3; ++i)
                v[r][i] = *(const float4*)(vr + 256 * i + 4 * l);
            vt[r] = thas ? vr[toff] : 0.f;
        }

        // raw dots q_r = y . v_r; DPP tree gives the full sum broadcast wave-uniform
        float p[W];
        #pragma unroll
        for (int r = 0; r < W; ++r) {
            float s = 0.f;
            #pragma unroll
            for (int i = 0; i < 3; ++i) {
                s += y[i].x * v[r][i].x + y[i].y * v[r][i].y
                   + y[i].z * v[r][i].z + y[i].w * v[r][i].w;
            }
            s += ytl * vt[r];                 // 0 on lanes >= 16
            p[r] = wave_red_sum(s);
        }

        // forward substitution (same formula & association as verified rounds), G from LDS
        float sv[W];
        #pragma unroll
        for (int r = 0; r < W; ++r) {
            float acc = p[r];
            #pragma unroll
            for (int k = 0; k < W; ++k)
                if (k < r) acc -= 2.f * Gw[k * 8 + r] * sv[k];
            sv[r] = acc;
        }

        // rank-8 update from the register copy of V
        #pragma unroll
        for (int r = 0; r < W; ++r) {
            float c = 2.f * sv[r];
            #pragma unroll
            for (int i = 0; i < 3; ++i) {
                y[i].x -= c * v[r][i].x;  y[i].y -= c * v[r][i].y;
                y[i].z -= c * v[r][i].z;  y[i].w -= c * v[r][i].w;
            }
            ytl -= c * vt[r];                 // stays 0 on lanes >= 16
        }
    }

    #pragma unroll
    for (int i = 0; i < 3; ++i)
        *(float4*)(out + b * DD + 256 * i + 4 * l) = y[i];
    if (thas)
        out[b * DD + toff] = ytl;
}

// ---------------- launch ----------------
extern "C" void kernel_launch(void* const* d_in, const int* in_sizes, int n_in,
                              void* d_out, int out_size, void* d_ws, size_t ws_size,
                              hipStream_t stream) {
    const float* x      = (const float*)d_in[0];   // [B,D]
    const float* ld_in  = (const float*)d_in[1];   // [B]
    const float* dp     = (const float*)d_in[2];   // [N,D]
    const float* log_hs = (const float*)d_in[3];   // [N,D]
    const float* kw     = (const float*)d_in[4];   // [N,D]
    const float* vs     = (const float*)d_in[5];   // [D,D]
    float* out = (float*)d_out;                    // x_out [B,D] then log_det [B]

    float* ws   = (float*)d_ws;
    float* lsew = ws;                         // 784 (pad to 1024)
    float4* pk  = (float4*)(ws + 1024);       // N*D float4
    float* Y    = ws + 1024 + NP * DD * 4;    // B*D
    float* T    = Y + BB * DD;                // B*D
    float* VN   = T + BB * DD;                // D*D
    float* G    = VN + DD * DD;               // NW*64 = 6272

    k_lsew<<<DD, 256, 0, stream>>>(kw, lsew);
    k_prep<<<NP, 256, 0, stream>>>(kw, log_hs, dp, lsew, pk);
    k_main<<<(BB * DD) / 256, 256, 0, stream>>>(x, pk, Y, T);
    k_logdet<<<BB, 256, 0, stream>>>(T, ld_in, out);
    k_vn<<<DD, 256, 0, stream>>>(vs, VN);
    k_gram<<<NW, 64, 0, stream>>>(VN, G);
    k_house<<<BB, 64, 0, stream>>>(Y, VN, G, out);
}

// Round 19
// 247.843 us; speedup vs baseline: 1.3573x; 1.0416x over previous
//
#include <hip/hip_runtime.h>
#include <math.h>

#define NP 256   // datapoints
#define BB 128   // batch
#define DD 784   // dims
#define HS_MIN 1e-7f
#define LOG_HS_MIN -16.11809565095832f   // log(1e-7)
#define LOG_MB -16.811242831518264f      // log(5e-8) — mask bound in log space
#define NEG_HALF_LOG_2PI -0.9189385332046727f
#define W 8      // householder window
#define NW 98    // 784/8

// ---------------- ndtri (AS241, double poly) from log_cdf / log_sf ----------------
__device__ double ndtri_logs(float log_cdf_f, float log_sf_f) {
    double lp = (double)log_cdf_f;
    double ls = (double)log_sf_f;
    double p = (double)__expf(log_cdf_f);
    double q = p - 0.5;
    if (fabs(q) <= 0.425) {
        double r = 0.180625 - q * q;
        double num = (((((((2.5090809287301226727e3 * r + 3.3430575583588128105e4) * r
                         + 6.7265770927008700853e4) * r + 4.5921953931549871457e4) * r
                         + 1.3731693765509461125e4) * r + 1.9715909503065514427e3) * r
                         + 1.3314166789178437745e2) * r + 3.3871328727963666080e0);
        double den = (((((((5.2264952788528545610e3 * r + 2.8729085735721942674e4) * r
                         + 3.9307895800092710610e4) * r + 2.1213794301586595867e4) * r
                         + 5.3941960214247511077e3) * r + 6.8718700749205790830e2) * r
                         + 4.2313330701600911252e1) * r + 1.0);
        return q * num / den;
    }
    // tail: r = sqrt(-log(min(p,1-p))) straight from the log — no 1-p cancellation
    double r = (q < 0.0) ? sqrt(-lp) : sqrt(-ls);
    double v;
    if (r <= 5.0) {
        r -= 1.6;
        double num = (((((((7.74545014278341407640e-4 * r + 2.27238449892691845833e-2) * r
                         + 2.41780725177450611770e-1) * r + 1.27045825245236838258e0) * r
                         + 3.64784832476320460504e0) * r + 5.76949722146069140550e0) * r
                         + 4.63033784615654529590e0) * r + 1.42343711074968357734e0);
        double den = (((((((1.05075007164441684324e-9 * r + 5.47593808499534494600e-4) * r
                         + 1.51986665636164571966e-2) * r + 1.48103976427480074590e-1) * r
                         + 6.89767334985100004550e-1) * r + 1.67638483018380384940e0) * r
                         + 2.05319162663775882187e0) * r + 1.0);
        v = num / den;
    } else {
        r -= 5.0;
        double num = (((((((2.01033439929228813265e-7 * r + 2.71155556874348757815e-5) * r
                         + 1.24266094738807843860e-3) * r + 2.65321895265761230930e-2) * r
                         + 2.96560571828504891230e-1) * r + 1.78482653991729133580e0) * r
                         + 5.46378491116411436990e0) * r + 6.65790464350110377720e0);
        double den = (((((((2.04426310338993978564e-15 * r + 1.42151175831644588870e-7) * r
                         + 1.84631831751005468180e-5) * r + 7.86869131145613259100e-4) * r
                         + 1.48753612908506148525e-2) * r + 1.36929880922735805310e-1) * r
                         + 5.99832206555887937690e-1) * r + 1.0);
        v = num / den;
    }
    return (q < 0.0) ? -v : v;
}

// ---------------- K0: fused lsew + prep (block per d) ----------------
// lse over n uses k_lsew's verbatim reduction (bit-identical lsew); then each thread n
// computes its pk entry with the round-18 formulas (bit-identical values; only the
// write pattern is scattered). Removes one dispatch + gap.
__global__ __launch_bounds__(256) void k_lseprep(const float* __restrict__ kw,
                                                 const float* __restrict__ log_hs,
                                                 const float* __restrict__ dp,
                                                 float4* __restrict__ pk) {
    __shared__ float red[4];
    int d = blockIdx.x;
    int n = threadIdx.x;          // NP == 256 == blockDim
    float a = kw[n * DD + d];
    float m = a;
    #pragma unroll
    for (int off = 32; off; off >>= 1) m = fmaxf(m, __shfl_xor(m, off, 64));
    if ((threadIdx.x & 63) == 0) red[threadIdx.x >> 6] = m;
    __syncthreads();
    m = fmaxf(fmaxf(red[0], red[1]), fmaxf(red[2], red[3]));
    __syncthreads();
    float e = __expf(a - m);
    #pragma unroll
    for (int off = 32; off; off >>= 1) e += __shfl_xor(e, off, 64);
    if ((threadIdx.x & 63) == 0) red[threadIdx.x >> 6] = e;
    __syncthreads();
    float lse = m + __logf(red[0] + red[1] + red[2] + red[3]);

    int idx = n * DD + d;
    float lh = log_hs[idx];
    float hs = fmaxf(__expf(lh), HS_MIN);
    float lhc = fmaxf(lh, LOG_HS_MIN);
    float wv = kw[idx] - lse;
    pk[idx] = make_float4(dp[idx], 1.f / hs, __expf(wv), __expf(wv - lhc));
}

// ---------------- K1: fused vn + gram (block per 8-row window) ----------------
// Stage 8 rows to LDS; per-row norm with k_vn's exact reduction tree (bit-identical
// inorm); normalize into LDS + global VN (bit-identical); Gram from LDS with k_gram's
// exact float4 accumulation order (bit-identical G). Removes one dispatch + gap and
// k_gram's latency-exposed global reads.
__global__ __launch_bounds__(256) void k_vngram(const float* __restrict__ vs,
                                                float* __restrict__ VN,
                                                float* __restrict__ G) {
    __shared__ float L[W * DD];       // 25088 B
    __shared__ float red[4];
    __shared__ float nrm[W];
    int wi = blockIdx.x;
    int t = threadIdx.x;
    const float* src = vs + (size_t)wi * (W * DD);
    for (int j = t; j < W * DD; j += 256) L[j] = src[j];
    __syncthreads();

    for (int r = 0; r < W; ++r) {
        float ss = 0.f;
        for (int j = t; j < DD; j += 256) {
            float v = L[r * DD + j];
            ss += v * v;
        }
        #pragma unroll
        for (int off = 32; off; off >>= 1) ss += __shfl_down(ss, off, 64);
        if ((t & 63) == 0) red[t >> 6] = ss;
        __syncthreads();
        if (t == 0) nrm[r] = rsqrtf(red[0] + red[1] + red[2] + red[3]);
        __syncthreads();          // guards nrm write AND red reuse next r
    }

    for (int j = t; j < W * DD; j += 256) {
        int r = j / DD;
        float v = L[j] * nrm[r];
        L[j] = v;
        VN[(size_t)wi * (W * DD) + j] = v;
    }
    __syncthreads();

    if (t < 64) {
        int k = t >> 3, i = t & 7;
        const float4* a = (const float4*)(L + k * DD);
        const float4* b = (const float4*)(L + i * DD);
        float s = 0.f;
        for (int j = 0; j < DD / 4; ++j) {
            float4 av = a[j], bv = b[j];
            s += av.x * bv.x + av.y * bv.y + av.z * bv.z + av.w * bv.w;
        }
        G[wi * 64 + k * 8 + i] = s;   // G[w][k][i] = v_k . v_i
    }
}

// ---------------- K2: main KDE + inverse + term — sigmoid closed form (round 18, verified) ----------------
__global__ __launch_bounds__(256) void k_main(const float* __restrict__ x,
                                              const float4* __restrict__ pk,
                                              float* __restrict__ Y,
                                              float* __restrict__ T) {
    unsigned t = blockIdx.x * 256u + threadIdx.x;   // t < B*D exactly
    unsigned b = t / DD;
    unsigned d = t - b * DD;
    float xv = x[t];
    float s1 = 0.f, s2 = 0.f, s3 = 0.f;
    for (int n = 0; n < NP; ++n) {
        float4 c = pk[n * DD + d];          // {dp, ihs, ew, ewl}
        float u = (c.x - xv) * c.y;
        float e = __expf(-fabsf(u));
        float r = 1.f / (1.f + e);
        float base = c.z * r;
        float eh = (u >= 0.f) ? e : 1.f;
        float el = (u >= 0.f) ? 1.f : e;
        s1 += base * eh;
        s2 += base * el;
        s3 += c.w * (e * r * r);
    }
    float log_cdf = __logf(s1);
    float log_sf  = __logf(s2);
    float log_pdf = __logf(s3);

    bool right = (log_sf  <= LOG_MB);
    bool left  = (log_cdf <= LOG_MB);

    float inv, lgd;
    if (right) {
        float t2 = -2.f * log_sf;
        inv = sqrtf(t2);
        lgd = 0.5f * __logf(t2) - log_sf;
    } else if (left) {
        float t2 = -2.f * log_cdf;
        inv = -sqrtf(t2);
        lgd = 0.5f * __logf(t2) - log_cdf;
    } else {
        inv = (float)ndtri_logs(log_cdf, log_sf);
        lgd = -0.5f * inv * inv + NEG_HALF_LOG_2PI;
    }
    Y[t] = inv;
    T[t] = log_pdf - lgd;
}

// ---------------- DPP wave64 sum: 6 VALU steps + readlane (no LDS pipe) ----------------
// Verified rounds 10-18 (passed, absmax 1.0). Full 64-lane sum, wave-uniform.
__device__ __forceinline__ float wave_red_sum(float x) {
    x += __int_as_float(__builtin_amdgcn_update_dpp(0, __float_as_int(x), 0x111, 0xf, 0xf, true));
    x += __int_as_float(__builtin_amdgcn_update_dpp(0, __float_as_int(x), 0x112, 0xf, 0xf, true));
    x += __int_as_float(__builtin_amdgcn_update_dpp(0, __float_as_int(x), 0x114, 0xf, 0xf, true));
    x += __int_as_float(__builtin_amdgcn_update_dpp(0, __float_as_int(x), 0x118, 0xf, 0xf, true));
    x += __int_as_float(__builtin_amdgcn_update_dpp(0, __float_as_int(x), 0x142, 0xa, 0xf, true));
    x += __int_as_float(__builtin_amdgcn_update_dpp(0, __float_as_int(x), 0x143, 0xc, 0xf, true));
    return __int_as_float(__builtin_amdgcn_readlane(__float_as_int(x), 63));
}

// ---------------- K3: Householder chain (round-15 exact, 131us floor) + fused log_det ----------------
// Window loop untouched (seven structures bracket it at 131us). Added: log_det
// prologue — block b sums T[b*784..] with the verified DPP tree and writes
// out[BB*DD+b] before the chain (T is ready: k_main precedes). Removes the
// k_logdet dispatch + gap.
__global__ __launch_bounds__(64, 1) void k_house(const float* __restrict__ Yin,
                                                 const float* __restrict__ T,
                                                 const float* __restrict__ ld_in,
                                                 const float* __restrict__ VN,
                                                 const float* __restrict__ G,
                                                 float* __restrict__ out) {
    __shared__ float gld[NW * 64];        // 25088 B: entire G table, staged once
    const int b = blockIdx.x;
    const int l = threadIdx.x;
    const int toff = 768 + (l & 15);      // clamped tail address (in-bounds all lanes)
    const bool thas = (l < 16);

    // fused log_det: DPP-tree sum of T[b]
    {
        float s = 0.f;
        #pragma unroll
        for (int i = 0; i < 12; ++i) s += T[b * DD + 64 * i + l];
        if (thas) s += T[b * DD + 768 + l];
        float tot = wave_red_sum(s);
        if (l == 0) out[BB * DD + b] = ld_in[b] + tot;
    }

    // one-time G stage: 98 coalesced dword loads per lane-stripe
    for (int i = l; i < NW * 64; i += 64) gld[i] = G[i];
    __syncthreads();

    float4 y[3];
    float ytl;
    #pragma unroll
    for (int i = 0; i < 3; ++i)
        y[i] = *(const float4*)(Yin + b * DD + 256 * i + 4 * l);
    ytl = thas ? Yin[b * DD + toff] : 0.f;

    for (int wi = 0; wi < NW; ++wi) {
        const float* Vw = VN + (size_t)wi * (W * DD);
        const float* Gw = gld + wi * 64;  // LDS: substitution never touches vmcnt

        // window's 8 V rows: 3 float4 + 1 tail scalar per lane (104 floats)
        float4 v[W][3];
        float vt[W];
        #pragma unroll
        for (int r = 0; r < W; ++r) {
            const float* vr = Vw + r * DD;
            #pragma unroll
            for (int i = 0; i < 3; ++i)
                v[r][i] = *(const float4*)(vr + 256 * i + 4 * l);
            vt[r] = thas ? vr[toff] : 0.f;
        }

        // raw dots q_r = y . v_r; DPP tree gives the full sum broadcast wave-uniform
        float p[W];
        #pragma unroll
        for (int r = 0; r < W; ++r) {
            float s = 0.f;
            #pragma unroll
            for (int i = 0; i < 3; ++i) {
                s += y[i].x * v[r][i].x + y[i].y * v[r][i].y
                   + y[i].z * v[r][i].z + y[i].w * v[r][i].w;
            }
            s += ytl * vt[r];                 // 0 on lanes >= 16
            p[r] = wave_red_sum(s);
        }

        // forward substitution (same formula & association as verified rounds), G from LDS
        float sv[W];
        #pragma unroll
        for (int r = 0; r < W; ++r) {
            float acc = p[r];
            #pragma unroll
            for (int k = 0; k < W; ++k)
                if (k < r) acc -= 2.f * Gw[k * 8 + r] * sv[k];
            sv[r] = acc;
        }

        // rank-8 update from the register copy of V
        #pragma unroll
        for (int r = 0; r < W; ++r) {
            float c = 2.f * sv[r];
            #pragma unroll
            for (int i = 0; i < 3; ++i) {
                y[i].x -= c * v[r][i].x;  y[i].y -= c * v[r][i].y;
                y[i].z -= c * v[r][i].z;  y[i].w -= c * v[r][i].w;
            }
            ytl -= c * vt[r];                 // stays 0 on lanes >= 16
        }
    }

    #pragma unroll
    for (int i = 0; i < 3; ++i)
        *(float4*)(out + b * DD + 256 * i + 4 * l) = y[i];
    if (thas)
        out[b * DD + toff] = ytl;
}

// ---------------- launch: 4 dispatches (was 7) ----------------
extern "C" void kernel_launch(void* const* d_in, const int* in_sizes, int n_in,
                              void* d_out, int out_size, void* d_ws, size_t ws_size,
                              hipStream_t stream) {
    const float* x      = (const float*)d_in[0];   // [B,D]
    const float* ld_in  = (const float*)d_in[1];   // [B]
    const float* dp     = (const float*)d_in[2];   // [N,D]
    const float* log_hs = (const float*)d_in[3];   // [N,D]
    const float* kw     = (const float*)d_in[4];   // [N,D]
    const float* vs     = (const float*)d_in[5];   // [D,D]
    float* out = (float*)d_out;                    // x_out [B,D] then log_det [B]

    float* ws   = (float*)d_ws;
    float4* pk  = (float4*)(ws + 1024);       // N*D float4
    float* Y    = ws + 1024 + NP * DD * 4;    // B*D
    float* T    = Y + BB * DD;                // B*D
    float* VN   = T + BB * DD;                // D*D
    float* G    = VN + DD * DD;               // NW*64 = 6272

    k_lseprep<<<DD, 256, 0, stream>>>(kw, log_hs, dp, pk);
    k_vngram<<<NW, 256, 0, stream>>>(vs, VN, G);
    k_main<<<(BB * DD) / 256, 256, 0, stream>>>(x, pk, Y, T);
    k_house<<<BB, 64, 0, stream>>>(Y, T, ld_in, VN, G, out);
}

// Round 20
// 235.279 us; speedup vs baseline: 1.4298x; 1.0534x over previous
//
#include <hip/hip_runtime.h>
#include <math.h>

#define NP 256   // datapoints
#define BB 128   // batch
#define DD 784   // dims
#define HS_MIN 1e-7f
#define LOG_HS_MIN -16.11809565095832f   // log(1e-7)
#define LOG_MB -16.811242831518264f      // log(5e-8) — mask bound in log space
#define NEG_HALF_LOG_2PI -0.9189385332046727f
#define W 8      // householder window
#define NW 98    // 784/8

// ---------------- ndtri (AS241, double poly) from log_cdf / log_sf ----------------
__device__ double ndtri_logs(float log_cdf_f, float log_sf_f) {
    double lp = (double)log_cdf_f;
    double ls = (double)log_sf_f;
    double p = (double)__expf(log_cdf_f);
    double q = p - 0.5;
    if (fabs(q) <= 0.425) {
        double r = 0.180625 - q * q;
        double num = (((((((2.5090809287301226727e3 * r + 3.3430575583588128105e4) * r
                         + 6.7265770927008700853e4) * r + 4.5921953931549871457e4) * r
                         + 1.3731693765509461125e4) * r + 1.9715909503065514427e3) * r
                         + 1.3314166789178437745e2) * r + 3.3871328727963666080e0);
        double den = (((((((5.2264952788528545610e3 * r + 2.8729085735721942674e4) * r
                         + 3.9307895800092710610e4) * r + 2.1213794301586595867e4) * r
                         + 5.3941960214247511077e3) * r + 6.8718700749205790830e2) * r
                         + 4.2313330701600911252e1) * r + 1.0);
        return q * num / den;
    }
    // tail: r = sqrt(-log(min(p,1-p))) straight from the log — no 1-p cancellation
    double r = (q < 0.0) ? sqrt(-lp) : sqrt(-ls);
    double v;
    if (r <= 5.0) {
        r -= 1.6;
        double num = (((((((7.74545014278341407640e-4 * r + 2.27238449892691845833e-2) * r
                         + 2.41780725177450611770e-1) * r + 1.27045825245236838258e0) * r
                         + 3.64784832476320460504e0) * r + 5.76949722146069140550e0) * r
                         + 4.63033784615654529590e0) * r + 1.42343711074968357734e0);
        double den = (((((((1.05075007164441684324e-9 * r + 5.47593808499534494600e-4) * r
                         + 1.51986665636164571966e-2) * r + 1.48103976427480074590e-1) * r
                         + 6.89767334985100004550e-1) * r + 1.67638483018380384940e0) * r
                         + 2.05319162663775882187e0) * r + 1.0);
        v = num / den;
    } else {
        r -= 5.0;
        double num = (((((((2.01033439929228813265e-7 * r + 2.71155556874348757815e-5) * r
                         + 1.24266094738807843860e-3) * r + 2.65321895265761230930e-2) * r
                         + 2.96560571828504891230e-1) * r + 1.78482653991729133580e0) * r
                         + 5.46378491116411436990e0) * r + 6.65790464350110377720e0);
        double den = (((((((2.04426310338993978564e-15 * r + 1.42151175831644588870e-7) * r
                         + 1.84631831751005468180e-5) * r + 7.86869131145613259100e-4) * r
                         + 1.48753612908506148525e-2) * r + 1.36929880922735805310e-1) * r
                         + 5.99832206555887937690e-1) * r + 1.0);
        v = num / den;
    }
    return (q < 0.0) ? -v : v;
}

// ---------------- K0: fully fused KDE — lse + pk(LDS) + main (block per d) ----------------
// pk[:,d] never touches global memory: block d computes it into LDS (4 KB) and
// consumes it immediately. Phase 1 is k_lsew's verbatim reduction (bit-identical lse);
// phase 2 the round-18 pk formulas (bit-identical values); phase 3 threads 0..127 run
// the exact round-18 inner loop over pkL[0..255] (same n-order, same bits; LDS reads
// are wave-broadcast => conflict-free) + the exact epilogue. Outputs bit-identical to
// round 19; removes pk's 3.2MB write + 3.2MB read, k_main's L2-latency loop, and one
// dispatch + gap.
__global__ __launch_bounds__(256) void k_kde(const float* __restrict__ kw,
                                             const float* __restrict__ log_hs,
                                             const float* __restrict__ dp,
                                             const float* __restrict__ x,
                                             float* __restrict__ Y,
                                             float* __restrict__ T) {
    __shared__ float red[4];
    __shared__ float4 pkL[NP];
    int d = blockIdx.x;
    int n = threadIdx.x;          // NP == 256 == blockDim

    // phase 1: lse over n (verbatim k_lsew reduction)
    float a = kw[n * DD + d];
    float m = a;
    #pragma unroll
    for (int off = 32; off; off >>= 1) m = fmaxf(m, __shfl_xor(m, off, 64));
    if ((n & 63) == 0) red[n >> 6] = m;
    __syncthreads();
    m = fmaxf(fmaxf(red[0], red[1]), fmaxf(red[2], red[3]));
    __syncthreads();
    float e = __expf(a - m);
    #pragma unroll
    for (int off = 32; off; off >>= 1) e += __shfl_xor(e, off, 64);
    if ((n & 63) == 0) red[n >> 6] = e;
    __syncthreads();
    float lse = m + __logf(red[0] + red[1] + red[2] + red[3]);

    // phase 2: pk entry into LDS (round-18 formulas, bit-identical values)
    {
        int idx = n * DD + d;
        float lh = log_hs[idx];
        float hs = fmaxf(__expf(lh), HS_MIN);
        float lhc = fmaxf(lh, LOG_HS_MIN);
        float wv = a - lse;               // a == kw[idx]
        pkL[n] = make_float4(dp[idx], 1.f / hs, __expf(wv), __expf(wv - lhc));
    }
    __syncthreads();

    // phase 3: threads 0..127 each own batch row b (exact round-18 loop + epilogue)
    if (n < BB) {
        int b = n;
        float xv = x[b * DD + d];
        float s1 = 0.f, s2 = 0.f, s3 = 0.f;
        for (int k = 0; k < NP; ++k) {
            float4 c = pkL[k];            // {dp, ihs, ew, ewl} — wave-broadcast read
            float u = (c.x - xv) * c.y;
            float ee = __expf(-fabsf(u));
            float r = 1.f / (1.f + ee);
            float base = c.z * r;
            float eh = (u >= 0.f) ? ee : 1.f;
            float el = (u >= 0.f) ? 1.f : ee;
            s1 += base * eh;
            s2 += base * el;
            s3 += c.w * (ee * r * r);
        }
        float log_cdf = __logf(s1);
        float log_sf  = __logf(s2);
        float log_pdf = __logf(s3);

        bool right = (log_sf  <= LOG_MB);
        bool left  = (log_cdf <= LOG_MB);

        float inv, lgd;
        if (right) {
            float t2 = -2.f * log_sf;
            inv = sqrtf(t2);
            lgd = 0.5f * __logf(t2) - log_sf;
        } else if (left) {
            float t2 = -2.f * log_cdf;
            inv = -sqrtf(t2);
            lgd = 0.5f * __logf(t2) - log_cdf;
        } else {
            inv = (float)ndtri_logs(log_cdf, log_sf);
            lgd = -0.5f * inv * inv + NEG_HALF_LOG_2PI;
        }
        Y[b * DD + d] = inv;
        T[b * DD + d] = log_pdf - lgd;
    }
}

// ---------------- K1: fused vn + gram (verified round 19) ----------------
__global__ __launch_bounds__(256) void k_vngram(const float* __restrict__ vs,
                                                float* __restrict__ VN,
                                                float* __restrict__ G) {
    __shared__ float L[W * DD];       // 25088 B
    __shared__ float red[4];
    __shared__ float nrm[W];
    int wi = blockIdx.x;
    int t = threadIdx.x;
    const float* src = vs + (size_t)wi * (W * DD);
    for (int j = t; j < W * DD; j += 256) L[j] = src[j];
    __syncthreads();

    for (int r = 0; r < W; ++r) {
        float ss = 0.f;
        for (int j = t; j < DD; j += 256) {
            float v = L[r * DD + j];
            ss += v * v;
        }
        #pragma unroll
        for (int off = 32; off; off >>= 1) ss += __shfl_down(ss, off, 64);
        if ((t & 63) == 0) red[t >> 6] = ss;
        __syncthreads();
        if (t == 0) nrm[r] = rsqrtf(red[0] + red[1] + red[2] + red[3]);
        __syncthreads();          // guards nrm write AND red reuse next r
    }

    for (int j = t; j < W * DD; j += 256) {
        int r = j / DD;
        float v = L[j] * nrm[r];
        L[j] = v;
        VN[(size_t)wi * (W * DD) + j] = v;
    }
    __syncthreads();

    if (t < 64) {
        int k = t >> 3, i = t & 7;
        const float4* a = (const float4*)(L + k * DD);
        const float4* b = (const float4*)(L + i * DD);
        float s = 0.f;
        for (int j = 0; j < DD / 4; ++j) {
            float4 av = a[j], bv = b[j];
            s += av.x * bv.x + av.y * bv.y + av.z * bv.z + av.w * bv.w;
        }
        G[wi * 64 + k * 8 + i] = s;   // G[w][k][i] = v_k . v_i
    }
}

// ---------------- DPP wave64 sum: 6 VALU steps + readlane (no LDS pipe) ----------------
// Verified rounds 10-19 (passed, absmax 1.0). Full 64-lane sum, wave-uniform.
__device__ __forceinline__ float wave_red_sum(float x) {
    x += __int_as_float(__builtin_amdgcn_update_dpp(0, __float_as_int(x), 0x111, 0xf, 0xf, true));
    x += __int_as_float(__builtin_amdgcn_update_dpp(0, __float_as_int(x), 0x112, 0xf, 0xf, true));
    x += __int_as_float(__builtin_amdgcn_update_dpp(0, __float_as_int(x), 0x114, 0xf, 0xf, true));
    x += __int_as_float(__builtin_amdgcn_update_dpp(0, __float_as_int(x), 0x118, 0xf, 0xf, true));
    x += __int_as_float(__builtin_amdgcn_update_dpp(0, __float_as_int(x), 0x142, 0xa, 0xf, true));
    x += __int_as_float(__builtin_amdgcn_update_dpp(0, __float_as_int(x), 0x143, 0xc, 0xf, true));
    return __int_as_float(__builtin_amdgcn_readlane(__float_as_int(x), 63));
}

// ---------------- K2: Householder chain (round-15 exact, 131us floor) + fused log_det ----------------
// Verified round 19. Window loop untouched (seven structures bracket it at 131us).
__global__ __launch_bounds__(64, 1) void k_house(const float* __restrict__ Yin,
                                                 const float* __restrict__ T,
                                                 const float* __restrict__ ld_in,
                                                 const float* __restrict__ VN,
                                                 const float* __restrict__ G,
                                                 float* __restrict__ out) {
    __shared__ float gld[NW * 64];        // 25088 B: entire G table, staged once
    const int b = blockIdx.x;
    const int l = threadIdx.x;
    const int toff = 768 + (l & 15);      // clamped tail address (in-bounds all lanes)
    const bool thas = (l < 16);

    // fused log_det: DPP-tree sum of T[b]
    {
        float s = 0.f;
        #pragma unroll
        for (int i = 0; i < 12; ++i) s += T[b * DD + 64 * i + l];
        if (thas) s += T[b * DD + 768 + l];
        float tot = wave_red_sum(s);
        if (l == 0) out[BB * DD + b] = ld_in[b] + tot;
    }

    // one-time G stage: 98 coalesced dword loads per lane-stripe
    for (int i = l; i < NW * 64; i += 64) gld[i] = G[i];
    __syncthreads();

    float4 y[3];
    float ytl;
    #pragma unroll
    for (int i = 0; i < 3; ++i)
        y[i] = *(const float4*)(Yin + b * DD + 256 * i + 4 * l);
    ytl = thas ? Yin[b * DD + toff] : 0.f;

    for (int wi = 0; wi < NW; ++wi) {
        const float* Vw = VN + (size_t)wi * (W * DD);
        const float* Gw = gld + wi * 64;  // LDS: substitution never touches vmcnt

        // window's 8 V rows: 3 float4 + 1 tail scalar per lane (104 floats)
        float4 v[W][3];
        float vt[W];
        #pragma unroll
        for (int r = 0; r < W; ++r) {
            const float* vr = Vw + r * DD;
            #pragma unroll
            for (int i = 0; i < 3; ++i)
                v[r][i] = *(const float4*)(vr + 256 * i + 4 * l);
            vt[r] = thas ? vr[toff] : 0.f;
        }

        // raw dots q_r = y . v_r; DPP tree gives the full sum broadcast wave-uniform
        float p[W];
        #pragma unroll
        for (int r = 0; r < W; ++r) {
            float s = 0.f;
            #pragma unroll
            for (int i = 0; i < 3; ++i) {
                s += y[i].x * v[r][i].x + y[i].y * v[r][i].y
                   + y[i].z * v[r][i].z + y[i].w * v[r][i].w;
            }
            s += ytl * vt[r];                 // 0 on lanes >= 16
            p[r] = wave_red_sum(s);
        }

        // forward substitution (same formula & association as verified rounds), G from LDS
        float sv[W];
        #pragma unroll
        for (int r = 0; r < W; ++r) {
            float acc = p[r];
            #pragma unroll
            for (int k = 0; k < W; ++k)
                if (k < r) acc -= 2.f * Gw[k * 8 + r] * sv[k];
            sv[r] = acc;
        }

        // rank-8 update from the register copy of V
        #pragma unroll
        for (int r = 0; r < W; ++r) {
            float c = 2.f * sv[r];
            #pragma unroll
            for (int i = 0; i < 3; ++i) {
                y[i].x -= c * v[r][i].x;  y[i].y -= c * v[r][i].y;
                y[i].z -= c * v[r][i].z;  y[i].w -= c * v[r][i].w;
            }
            ytl -= c * vt[r];                 // stays 0 on lanes >= 16
        }
    }

    #pragma unroll
    for (int i = 0; i < 3; ++i)
        *(float4*)(out + b * DD + 256 * i + 4 * l) = y[i];
    if (thas)
        out[b * DD + toff] = ytl;
}

// ---------------- launch: 3 dispatches (was 4) ----------------
extern "C" void kernel_launch(void* const* d_in, const int* in_sizes, int n_in,
                              void* d_out, int out_size, void* d_ws, size_t ws_size,
                              hipStream_t stream) {
    const float* x      = (const float*)d_in[0];   // [B,D]
    const float* ld_in  = (const float*)d_in[1];   // [B]
    const float* dp     = (const float*)d_in[2];   // [N,D]
    const float* log_hs = (const float*)d_in[3];   // [N,D]
    const float* kw     = (const float*)d_in[4];   // [N,D]
    const float* vs     = (const float*)d_in[5];   // [D,D]
    float* out = (float*)d_out;                    // x_out [B,D] then log_det [B]

    float* ws   = (float*)d_ws;
    float* Y    = ws + 1024;                  // B*D
    float* T    = Y + BB * DD;                // B*D
    float* VN   = T + BB * DD;                // D*D
    float* G    = VN + DD * DD;               // NW*64 = 6272

    k_vngram<<<NW, 256, 0, stream>>>(vs, VN, G);
    k_kde<<<DD, 256, 0, stream>>>(kw, log_hs, dp, x, Y, T);
    k_house<<<BB, 64, 0, stream>>>(Y, T, ld_in, VN, G, out);
}

// Round 21
// 223.248 us; speedup vs baseline: 1.5068x; 1.0539x over previous
//
#include <hip/hip_runtime.h>
#include <math.h>

#define NP 256   // datapoints
#define BB 128   // batch
#define DD 784   // dims
#define HS_MIN 1e-7f
#define LOG_HS_MIN -16.11809565095832f   // log(1e-7)
#define LOG_MB -16.811242831518264f      // log(5e-8) — mask bound in log space
#define NEG_HALF_LOG_2PI -0.9189385332046727f
#define W 8      // householder window
#define NW 98    // 784/8

// ---------------- ndtri (AS241, double poly) from log_cdf / log_sf ----------------
__device__ double ndtri_logs(float log_cdf_f, float log_sf_f) {
    double lp = (double)log_cdf_f;
    double ls = (double)log_sf_f;
    double p = (double)__expf(log_cdf_f);
    double q = p - 0.5;
    if (fabs(q) <= 0.425) {
        double r = 0.180625 - q * q;
        double num = (((((((2.5090809287301226727e3 * r + 3.3430575583588128105e4) * r
                         + 6.7265770927008700853e4) * r + 4.5921953931549871457e4) * r
                         + 1.3731693765509461125e4) * r + 1.9715909503065514427e3) * r
                         + 1.3314166789178437745e2) * r + 3.3871328727963666080e0);
        double den = (((((((5.2264952788528545610e3 * r + 2.8729085735721942674e4) * r
                         + 3.9307895800092710610e4) * r + 2.1213794301586595867e4) * r
                         + 5.3941960214247511077e3) * r + 6.8718700749205790830e2) * r
                         + 4.2313330701600911252e1) * r + 1.0);
        return q * num / den;
    }
    // tail: r = sqrt(-log(min(p,1-p))) straight from the log — no 1-p cancellation
    double r = (q < 0.0) ? sqrt(-lp) : sqrt(-ls);
    double v;
    if (r <= 5.0) {
        r -= 1.6;
        double num = (((((((7.74545014278341407640e-4 * r + 2.27238449892691845833e-2) * r
                         + 2.41780725177450611770e-1) * r + 1.27045825245236838258e0) * r
                         + 3.64784832476320460504e0) * r + 5.76949722146069140550e0) * r
                         + 4.63033784615654529590e0) * r + 1.42343711074968357734e0);
        double den = (((((((1.05075007164441684324e-9 * r + 5.47593808499534494600e-4) * r
                         + 1.51986665636164571966e-2) * r + 1.48103976427480074590e-1) * r
                         + 6.89767334985100004550e-1) * r + 1.67638483018380384940e0) * r
                         + 2.05319162663775882187e0) * r + 1.0);
        v = num / den;
    } else {
        r -= 5.0;
        double num = (((((((2.01033439929228813265e-7 * r + 2.71155556874348757815e-5) * r
                         + 1.24266094738807843860e-3) * r + 2.65321895265761230930e-2) * r
                         + 2.96560571828504891230e-1) * r + 1.78482653991729133580e0) * r
                         + 5.46378491116411436990e0) * r + 6.65790464350110377720e0);
        double den = (((((((2.04426310338993978564e-15 * r + 1.42151175831644588870e-7) * r
                         + 1.84631831751005468180e-5) * r + 7.86869131145613259100e-4) * r
                         + 1.48753612908506148525e-2) * r + 1.36929880922735805310e-1) * r
                         + 5.99832206555887937690e-1) * r + 1.0);
        v = num / den;
    }
    return (q < 0.0) ? -v : v;
}

// ---------------- K0: fused {vn+gram | lse+pk+main} — uniform branch on blockIdx ----------------
// Blocks [0,NW): k_vngram verbatim (round 19, verified). Blocks [NW, NW+DD): k_kde with
// phase 3 split across all 256 threads: thread n owns row b=n&127, half h=n>>7, summing
// k in [128h,128h+128) with the exact round-20 loop body (+unroll for ILP); half-1
// publishes partials to LDS, one barrier, half-0 combines (s = s_h0 + s_h1 — one
// reassociation, same risk class as rounds 10/18) and runs the exact epilogue.
// Halves the serial dependent chain and doubles active waves per block.
__global__ __launch_bounds__(256) void k_fused(const float* __restrict__ vs,
                                               float* __restrict__ VN,
                                               float* __restrict__ G,
                                               const float* __restrict__ kw,
                                               const float* __restrict__ log_hs,
                                               const float* __restrict__ dp,
                                               const float* __restrict__ x,
                                               float* __restrict__ Y,
                                               float* __restrict__ T) {
    __shared__ __align__(16) float smem[W * DD + 16];   // 25152 B, dual-purpose
    int t = threadIdx.x;

    if (blockIdx.x < NW) {
        // ---------- vn + gram branch (verbatim round 19) ----------
        float* L   = smem;                 // [W*DD]
        float* red = smem + W * DD;        // [4]
        float* nrm = smem + W * DD + 4;    // [W]
        int wi = blockIdx.x;
        const float* src = vs + (size_t)wi * (W * DD);
        for (int j = t; j < W * DD; j += 256) L[j] = src[j];
        __syncthreads();

        for (int r = 0; r < W; ++r) {
            float ss = 0.f;
            for (int j = t; j < DD; j += 256) {
                float v = L[r * DD + j];
                ss += v * v;
            }
            #pragma unroll
            for (int off = 32; off; off >>= 1) ss += __shfl_down(ss, off, 64);
            if ((t & 63) == 0) red[t >> 6] = ss;
            __syncthreads();
            if (t == 0) nrm[r] = rsqrtf(red[0] + red[1] + red[2] + red[3]);
            __syncthreads();          // guards nrm write AND red reuse next r
        }

        for (int j = t; j < W * DD; j += 256) {
            int r = j / DD;
            float v = L[j] * nrm[r];
            L[j] = v;
            VN[(size_t)wi * (W * DD) + j] = v;
        }
        __syncthreads();

        if (t < 64) {
            int k = t >> 3, i = t & 7;
            const float4* a = (const float4*)(L + k * DD);
            const float4* b = (const float4*)(L + i * DD);
            float s = 0.f;
            for (int j = 0; j < DD / 4; ++j) {
                float4 av = a[j], bv = b[j];
                s += av.x * bv.x + av.y * bv.y + av.z * bv.z + av.w * bv.w;
            }
            G[wi * 64 + k * 8 + i] = s;   // G[w][k][i] = v_k . v_i
        }
        return;
    }

    // ---------- kde branch: lse + pk(LDS) + main ----------
    float*  red  = smem;                        // [4]
    float4* pkL  = (float4*)(smem + 4);         // [NP] — 16B-aligned (base+16B)
    float*  comb = smem + 4 + 4 * NP;           // [BB*3]
    int d = blockIdx.x - NW;
    int n = t;                                  // NP == 256 == blockDim

    // phase 1: lse over n (verbatim k_lsew reduction, bit-identical)
    float a = kw[n * DD + d];
    float m = a;
    #pragma unroll
    for (int off = 32; off; off >>= 1) m = fmaxf(m, __shfl_xor(m, off, 64));
    if ((n & 63) == 0) red[n >> 6] = m;
    __syncthreads();
    m = fmaxf(fmaxf(red[0], red[1]), fmaxf(red[2], red[3]));
    __syncthreads();
    float e = __expf(a - m);
    #pragma unroll
    for (int off = 32; off; off >>= 1) e += __shfl_xor(e, off, 64);
    if ((n & 63) == 0) red[n >> 6] = e;
    __syncthreads();
    float lse = m + __logf(red[0] + red[1] + red[2] + red[3]);

    // phase 2: pk entry into LDS (round-18 formulas, bit-identical values)
    {
        int idx = n * DD + d;
        float lh = log_hs[idx];
        float hs = fmaxf(__expf(lh), HS_MIN);
        float lhc = fmaxf(lh, LOG_HS_MIN);
        float wv = a - lse;               // a == kw[idx]
        pkL[n] = make_float4(dp[idx], 1.f / hs, __expf(wv), __expf(wv - lhc));
    }
    __syncthreads();

    // phase 3: all 256 threads; thread n -> row b = n&127, half h = n>>7
    int b = n & 127;
    int h = n >> 7;
    float xv = x[b * DD + d];
    float s1 = 0.f, s2 = 0.f, s3 = 0.f;
    int k0 = h * 128;
    #pragma unroll 4
    for (int k = k0; k < k0 + 128; ++k) {
        float4 c = pkL[k];            // {dp, ihs, ew, ewl} — wave-broadcast read
        float u = (c.x - xv) * c.y;
        float ee = __expf(-fabsf(u));
        float r = 1.f / (1.f + ee);
        float base = c.z * r;
        float eh = (u >= 0.f) ? ee : 1.f;
        float el = (u >= 0.f) ? 1.f : ee;
        s1 += base * eh;
        s2 += base * el;
        s3 += c.w * (ee * r * r);
    }
    if (h == 1) {
        comb[b * 3 + 0] = s1;
        comb[b * 3 + 1] = s2;
        comb[b * 3 + 2] = s3;
    }
    __syncthreads();
    if (h == 0) {
        s1 += comb[b * 3 + 0];
        s2 += comb[b * 3 + 1];
        s3 += comb[b * 3 + 2];
        float log_cdf = __logf(s1);
        float log_sf  = __logf(s2);
        float log_pdf = __logf(s3);

        bool right = (log_sf  <= LOG_MB);
        bool left  = (log_cdf <= LOG_MB);

        float inv, lgd;
        if (right) {
            float t2 = -2.f * log_sf;
            inv = sqrtf(t2);
            lgd = 0.5f * __logf(t2) - log_sf;
        } else if (left) {
            float t2 = -2.f * log_cdf;
            inv = -sqrtf(t2);
            lgd = 0.5f * __logf(t2) - log_cdf;
        } else {
            inv = (float)ndtri_logs(log_cdf, log_sf);
            lgd = -0.5f * inv * inv + NEG_HALF_LOG_2PI;
        }
        Y[b * DD + d] = inv;
        T[b * DD + d] = log_pdf - lgd;
    }
}

// ---------------- DPP wave64 sum: 6 VALU steps + readlane (no LDS pipe) ----------------
// Verified rounds 10-20 (passed, absmax 1.0). Full 64-lane sum, wave-uniform.
__device__ __forceinline__ float wave_red_sum(float x) {
    x += __int_as_float(__builtin_amdgcn_update_dpp(0, __float_as_int(x), 0x111, 0xf, 0xf, true));
    x += __int_as_float(__builtin_amdgcn_update_dpp(0, __float_as_int(x), 0x112, 0xf, 0xf, true));
    x += __int_as_float(__builtin_amdgcn_update_dpp(0, __float_as_int(x), 0x114, 0xf, 0xf, true));
    x += __int_as_float(__builtin_amdgcn_update_dpp(0, __float_as_int(x), 0x118, 0xf, 0xf, true));
    x += __int_as_float(__builtin_amdgcn_update_dpp(0, __float_as_int(x), 0x142, 0xa, 0xf, true));
    x += __int_as_float(__builtin_amdgcn_update_dpp(0, __float_as_int(x), 0x143, 0xc, 0xf, true));
    return __int_as_float(__builtin_amdgcn_readlane(__float_as_int(x), 63));
}

// ---------------- K1: Householder chain (round-15 exact, 131us floor) + fused log_det ----------------
// Verified rounds 19/20. Window loop untouched (seven structures bracket it at 131us).
__global__ __launch_bounds__(64, 1) void k_house(const float* __restrict__ Yin,
                                                 const float* __restrict__ T,
                                                 const float* __restrict__ ld_in,
                                                 const float* __restrict__ VN,
                                                 const float* __restrict__ G,
                                                 float* __restrict__ out) {
    __shared__ float gld[NW * 64];        // 25088 B: entire G table, staged once
    const int b = blockIdx.x;
    const int l = threadIdx.x;
    const int toff = 768 + (l & 15);      // clamped tail address (in-bounds all lanes)
    const bool thas = (l < 16);

    // fused log_det: DPP-tree sum of T[b]
    {
        float s = 0.f;
        #pragma unroll
        for (int i = 0; i < 12; ++i) s += T[b * DD + 64 * i + l];
        if (thas) s += T[b * DD + 768 + l];
        float tot = wave_red_sum(s);
        if (l == 0) out[BB * DD + b] = ld_in[b] + tot;
    }

    // one-time G stage: 98 coalesced dword loads per lane-stripe
    for (int i = l; i < NW * 64; i += 64) gld[i] = G[i];
    __syncthreads();

    float4 y[3];
    float ytl;
    #pragma unroll
    for (int i = 0; i < 3; ++i)
        y[i] = *(const float4*)(Yin + b * DD + 256 * i + 4 * l);
    ytl = thas ? Yin[b * DD + toff] : 0.f;

    for (int wi = 0; wi < NW; ++wi) {
        const float* Vw = VN + (size_t)wi * (W * DD);
        const float* Gw = gld + wi * 64;  // LDS: substitution never touches vmcnt

        // window's 8 V rows: 3 float4 + 1 tail scalar per lane (104 floats)
        float4 v[W][3];
        float vt[W];
        #pragma unroll
        for (int r = 0; r < W; ++r) {
            const float* vr = Vw + r * DD;
            #pragma unroll
            for (int i = 0; i < 3; ++i)
                v[r][i] = *(const float4*)(vr + 256 * i + 4 * l);
            vt[r] = thas ? vr[toff] : 0.f;
        }

        // raw dots q_r = y . v_r; DPP tree gives the full sum broadcast wave-uniform
        float p[W];
        #pragma unroll
        for (int r = 0; r < W; ++r) {
            float s = 0.f;
            #pragma unroll
            for (int i = 0; i < 3; ++i) {
                s += y[i].x * v[r][i].x + y[i].y * v[r][i].y
                   + y[i].z * v[r][i].z + y[i].w * v[r][i].w;
            }
            s += ytl * vt[r];                 // 0 on lanes >= 16
            p[r] = wave_red_sum(s);
        }

        // forward substitution (same formula & association as verified rounds), G from LDS
        float sv[W];
        #pragma unroll
        for (int r = 0; r < W; ++r) {
            float acc = p[r];
            #pragma unroll
            for (int k = 0; k < W; ++k)
                if (k < r) acc -= 2.f * Gw[k * 8 + r] * sv[k];
            sv[r] = acc;
        }

        // rank-8 update from the register copy of V
        #pragma unroll
        for (int r = 0; r < W; ++r) {
            float c = 2.f * sv[r];
            #pragma unroll
            for (int i = 0; i < 3; ++i) {
                y[i].x -= c * v[r][i].x;  y[i].y -= c * v[r][i].y;
                y[i].z -= c * v[r][i].z;  y[i].w -= c * v[r][i].w;
            }
            ytl -= c * vt[r];                 // stays 0 on lanes >= 16
        }
    }

    #pragma unroll
    for (int i = 0; i < 3; ++i)
        *(float4*)(out + b * DD + 256 * i + 4 * l) = y[i];
    if (thas)
        out[b * DD + toff] = ytl;
}

// ---------------- launch: 2 dispatches (was 3) ----------------
extern "C" void kernel_launch(void* const* d_in, const int* in_sizes, int n_in,
                              void* d_out, int out_size, void* d_ws, size_t ws_size,
                              hipStream_t stream) {
    const float* x      = (const float*)d_in[0];   // [B,D]
    const float* ld_in  = (const float*)d_in[1];   // [B]
    const float* dp     = (const float*)d_in[2];   // [N,D]
    const float* log_hs = (const float*)d_in[3];   // [N,D]
    const float* kw     = (const float*)d_in[4];   // [N,D]
    const float* vs     = (const float*)d_in[5];   // [D,D]
    float* out = (float*)d_out;                    // x_out [B,D] then log_det [B]

    float* ws   = (float*)d_ws;
    float* Y    = ws + 1024;                  // B*D
    float* T    = Y + BB * DD;                // B*D
    float* VN   = T + BB * DD;                // D*D
    float* G    = VN + DD * DD;               // NW*64 = 6272

    k_fused<<<NW + DD, 256, 0, stream>>>(vs, VN, G, kw, log_hs, dp, x, Y, T);
    k_house<<<BB, 64, 0, stream>>>(Y, T, ld_in, VN, G, out);
}